// Round 16
// baseline (288.732 us; speedup 1.0000x reference)
//
#include <hip/hip_runtime.h>

#define Bn 4
#define Cn 64
#define Hn 256
#define Wn 256
#define HWn 65536

typedef unsigned int u32;
typedef __attribute__((ext_vector_type(2))) unsigned int u32x2;
typedef __attribute__((ext_vector_type(8))) short bf16x8;
typedef __attribute__((ext_vector_type(4))) float f32x4;
typedef __attribute__((ext_vector_type(16))) float f32x16;

__device__ __forceinline__ unsigned short f2b(float f) {
    union { float f; unsigned u; } v; v.f = f;
    return (unsigned short)(v.u >> 16);
}
__device__ __forceinline__ float b2f(unsigned short s) {
    union { float f; unsigned u; } v; v.u = ((unsigned)s) << 16;
    return v.f;
}
__device__ __forceinline__ u32 cvtpk(float lo, float hi) {
    u32 r;
    asm("v_cvt_pk_bf16_f32 %0, %1, %2" : "=v"(r) : "v"(lo), "v"(hi));
    return r;
}
__device__ __forceinline__ void vswap(u32& a, u32& b) {
    asm volatile("v_permlane32_swap_b32 %0, %1" : "+v"(a), "+v"(b));
}
__device__ __forceinline__ float pair_other(float v, int lane) {
    union { float f; u32 u; } A; A.f = v;
    u32 a = A.u, b = A.u;
    vswap(a, b);
    union { u32 u; float f; } R; R.u = (lane < 32) ? b : a;
    return R.f;
}
__device__ __forceinline__ bf16x8 expPack(const f32x16& e, int base, float& ss) {
    float p0 = __expf(e[base + 0]), p1 = __expf(e[base + 1]);
    u32 A = cvtpk(p0, p1); ss += p0 + p1;
    float p4 = __expf(e[base + 4]), p5 = __expf(e[base + 5]);
    u32 B = cvtpk(p4, p5); ss += p4 + p5;
    vswap(A, B);
    float p2 = __expf(e[base + 2]), p3 = __expf(e[base + 3]);
    u32 C = cvtpk(p2, p3); ss += p2 + p3;
    float p6 = __expf(e[base + 6]), p7 = __expf(e[base + 7]);
    u32 D = cvtpk(p6, p7); ss += p6 + p7;
    vswap(C, D);
    union { u32 w[4]; bf16x8 v; } u;
    u.w[0] = A; u.w[1] = C; u.w[2] = B; u.w[3] = D;
    return u.v;
}

// ---------------- K1: persistent pipelined 1x1 conv projections ----------------
__global__ __launch_bounds__(256) void k_proj(
    const float* __restrict__ x,
    const float* __restrict__ Wq, const float* __restrict__ bq,
    const float* __restrict__ Wk, const float* __restrict__ bk,
    const float* __restrict__ Wv, const float* __restrict__ bv,
    unsigned short* __restrict__ qbr, unsigned short* __restrict__ kbr,
    unsigned short* __restrict__ v_row)
{
    __shared__ __align__(16) char Xl[2][16384];
    int t = threadIdx.x, lane = t & 63, wv = t >> 6;
    int row16 = lane & 15, g = lane >> 4;
    int u0 = blockIdx.x * 4;

    bf16x8 Af[5][2];
    #pragma unroll
    for (int m = 0; m < 5; ++m) {
        const float* wrow;
        if (m == 0) wrow = (row16 < 8) ? (Wq + row16 * 64) : (Wk + (row16 - 8) * 64);
        else        wrow = Wv + (size_t)((m - 1) * 16 + row16) * 64;
        #pragma unroll
        for (int ks = 0; ks < 2; ++ks) {
            int c0 = ks * 32 + g * 8;
            f32x4 w0 = *(const f32x4*)(wrow + c0);
            f32x4 w1 = *(const f32x4*)(wrow + c0 + 4);
            bf16x8 a;
            a[0] = (short)f2b(w0[0]); a[1] = (short)f2b(w0[1]);
            a[2] = (short)f2b(w0[2]); a[3] = (short)f2b(w0[3]);
            a[4] = (short)f2b(w1[0]); a[5] = (short)f2b(w1[1]);
            a[6] = (short)f2b(w1[2]); a[7] = (short)f2b(w1[3]);
            Af[m][ks] = a;
        }
    }

    int px4 = (t & 31) * 4;
    int cbase = (t >> 5) << 2;

    f32x4 st[2][8];
    {
        int u = u0;
        int b = u >> 9, rest = u & 511, h = rest >> 1, half = rest & 1;
        const float* xb2 = x + (size_t)b * Cn * HWn + (size_t)h * Wn + half * 128;
        #pragma unroll
        for (int pass = 0; pass < 2; ++pass) {
            int c0s = cbase + pass * 32;
            #pragma unroll
            for (int j = 0; j < 4; ++j)
                st[0][pass * 4 + j] = *(const f32x4*)(xb2 + (size_t)(c0s + j) * HWn + px4);
        }
    }

    #pragma unroll
    for (int ui = 0; ui < 4; ++ui) {
        int u = u0 + ui;
        int b = u >> 9, rest = u & 511, h = rest >> 1, half = rest & 1;
        int cur = ui & 1;

        #pragma unroll
        for (int pass = 0; pass < 2; ++pass) {
            int c0s = cbase + pass * 32;
            #pragma unroll
            for (int i = 0; i < 4; ++i) {
                int px = px4 + i;
                u32x2 w;
                w[0] = (u32)f2b(st[cur][pass * 4 + 0][i]) | ((u32)f2b(st[cur][pass * 4 + 1][i]) << 16);
                w[1] = (u32)f2b(st[cur][pass * 4 + 2][i]) | ((u32)f2b(st[cur][pass * 4 + 3][i]) << 16);
                unsigned addr = (unsigned)(px * 128)
                              + (((unsigned)(c0s * 2)) ^ ((((unsigned)px >> 3) & 7) << 4));
                *(u32x2*)(Xl[cur] + addr) = w;
            }
        }
        __syncthreads();

        if (ui < 3) {
            int un = u + 1;
            int bn = un >> 9, restn = un & 511, hn = restn >> 1, halfn = restn & 1;
            const float* xb2 = x + (size_t)bn * Cn * HWn + (size_t)hn * Wn + halfn * 128;
            #pragma unroll
            for (int pass = 0; pass < 2; ++pass) {
                int c0s = cbase + pass * 32;
                #pragma unroll
                for (int j = 0; j < 4; ++j)
                    st[cur ^ 1][pass * 4 + j] = *(const f32x4*)(xb2 + (size_t)(c0s + j) * HWn + px4);
            }
        }

        f32x4 acc[5][2];
        #pragma unroll
        for (int m = 0; m < 5; ++m)
            #pragma unroll
            for (int nt = 0; nt < 2; ++nt)
                acc[m][nt] = (f32x4){0.f, 0.f, 0.f, 0.f};

        #pragma unroll
        for (int nt = 0; nt < 2; ++nt) {
            int px = wv * 32 + nt * 16 + row16;
            #pragma unroll
            for (int ks = 0; ks < 2; ++ks) {
                int c0 = ks * 32 + g * 8;
                unsigned addr = (unsigned)(px * 128)
                              + (((unsigned)(c0 * 2)) ^ ((((unsigned)px >> 3) & 7) << 4));
                bf16x8 bf = *(const bf16x8*)(Xl[cur] + addr);
                #pragma unroll
                for (int m = 0; m < 5; ++m)
                    acc[m][nt] = __builtin_amdgcn_mfma_f32_16x16x32_bf16(Af[m][ks], bf, acc[m][nt], 0, 0, 0);
            }
        }

        f32x4 bQK = (g < 2) ? *(const f32x4*)(bq + g * 4)
                            : *(const f32x4*)(bk + (g - 2) * 4);
        #pragma unroll
        for (int nt = 0; nt < 2; ++nt) {
            int p = half * 128 + wv * 32 + nt * 16 + row16;
            f32x4 d = acc[0][nt];
            d[0] += bQK[0]; d[1] += bQK[1]; d[2] += bQK[2]; d[3] += bQK[3];
            u32 w0 = (u32)f2b(d[0]) | ((u32)f2b(d[1]) << 16);
            u32 w1 = (u32)f2b(d[2]) | ((u32)f2b(d[3]) << 16);
            size_t roff = ((size_t)(b * Hn + h) * Wn + p) * 8 + (size_t)((g & 1) * 4);
            if (g < 2) {
                *(u32*)(qbr + roff) = w0; *(u32*)(qbr + roff + 2) = w1;
            } else {
                *(u32*)(kbr + roff) = w0; *(u32*)(kbr + roff + 2) = w1;
            }
            #pragma unroll
            for (int m = 1; m < 5; ++m) {
                f32x4 bV = *(const f32x4*)(bv + (m - 1) * 16 + g * 4);
                unsigned short* vp = v_row + (size_t)b * Cn * HWn
                                   + (size_t)((m - 1) * 16 + g * 4) * HWn
                                   + (size_t)h * Wn + p;
                #pragma unroll
                for (int r = 0; r < 4; ++r)
                    vp[(size_t)r * HWn] = f2b(acc[m][nt][r] + bV[r]);
            }
        }
    }
}

// ---------------- bf16 tiled transpose (v_row -> vT only) ----------------
__global__ __launch_bounds__(256) void k_tr_bf16(
    const unsigned short* __restrict__ in, unsigned short* __restrict__ out,
    int R, int Ccols)
{
    __shared__ unsigned short tile[64][66];
    int t = threadIdx.x;
    int lr = t >> 6, lc = t & 63;
    int tilesC = Ccols >> 6;
    int per_b = (R >> 6) * tilesC;
    int bid = blockIdx.x;
    int b = bid / per_b;
    int rem = bid - b * per_b;
    int r0 = (rem / tilesC) << 6;
    int c0 = (rem - (rem / tilesC) * tilesC) << 6;
    const unsigned short* ip = in + (size_t)b * R * Ccols;
    unsigned short* op = out + (size_t)b * R * Ccols;
    #pragma unroll
    for (int i = 0; i < 16; ++i) {
        int r = lr * 16 + i;
        tile[r][lc] = ip[(size_t)(r0 + r) * Ccols + c0 + lc];
    }
    __syncthreads();
    #pragma unroll
    for (int i = 0; i < 16; ++i) {
        int c = lr * 16 + i;
        op[(size_t)(c0 + c) * R + r0 + lc] = tile[lc][c];
    }
}

// ---------------- K2: H-direction attention ----------------
// R16: 512-thread blocks (8 waves, full 256-q row) — breaks the 32KB-V LDS
// occupancy wall (V now shared by 8 waves; 36.9KB -> 4 blocks/CU = up to
// 32 waves). K staged in LDS (4KB) and read per-jt -> frees Kf's 32 VGPR;
// launch_bounds(512,6) caps VGPR ~85 for >=24 waves/CU. Spill guard:
// WRITE_SIZE must stay 65MB.
__global__ __launch_bounds__(512, 6) void k_attnH(
    const unsigned short* __restrict__ qbr, const unsigned short* __restrict__ kbr,
    const unsigned short* __restrict__ vT,
    unsigned short* __restrict__ ohp,
    float* __restrict__ sH)
{
    __shared__ __align__(16) unsigned short Vl[16384];
    __shared__ __align__(16) unsigned short Kl[2048];
    int t = threadIdx.x, lane = t & 63, wv = t >> 6;
    int l31 = lane & 31, hi = lane >> 5;
    int bid = blockIdx.x;
    int b = bid >> 8, w = bid & 255;

    const char* vsrc = (const char*)(vT + ((size_t)(b * Wn + w)) * Cn * Hn);
    #pragma unroll
    for (int p = 0; p < 4; ++p) {
        int lin = p * 8192 + t * 16;
        int c = lin >> 9;
        f32x4 d = *(const f32x4*)(vsrc + lin);
        unsigned dst = (unsigned)lin ^ ((unsigned)(c & 7) << 4);
        *(f32x4*)((char*)Vl + dst) = d;
    }
    if (t < 256) {
        *(bf16x8*)(Kl + t * 8) = *(const bf16x8*)(kbr + ((size_t)(b * Hn + t) * Wn + w) * 8);
    }

    bf16x8 zer = {};
    int qtA = wv;
    int q = qtA * 32 + l31;
    bf16x8 Qf;
    {
        bf16x8 v = *(const bf16x8*)(qbr + ((size_t)(b * Hn + q) * Wn + w) * 8);
        Qf = (hi == 0) ? v : zer;
    }
    __syncthreads();

    f32x16 Oa = {}, Ob = {};
    float s = 0.f;
    #pragma unroll
    for (int jt = 0; jt < 8; ++jt) {
        bf16x8 Kfc = *(const bf16x8*)(Kl + (jt * 32 + l31) * 8);
        if (hi) Kfc = zer;
        f32x16 zc = {};
        f32x16 e = __builtin_amdgcn_mfma_f32_32x32x16_bf16(Kfc, Qf, zc, 0, 0, 0);
        if (jt == qtA) {
            #pragma unroll
            for (int r = 0; r < 16; ++r) {
                int rl = (r & 3) + 8 * (r >> 2) + 4 * hi;
                e[r] = (rl == l31) ? -1e30f : e[r];
            }
        }
        bf16x8 P0 = expPack(e, 0, s);
        bf16x8 P1 = expPack(e, 8, s);
        #pragma unroll
        for (int k2 = 0; k2 < 2; ++k2) {
            int ktA = jt * 2 + k2;
            bf16x8 Pf = k2 ? P1 : P0;
            #pragma unroll
            for (int ct = 0; ct < 2; ++ct) {
                int c = ct * 32 + l31;
                unsigned ad = ((unsigned)(c * 512 + ktA * 32 + hi * 16))
                            ^ ((unsigned)(c & 7) << 4);
                bf16x8 Vf = *(const bf16x8*)((const char*)Vl + ad);
                if (ct == 0) Oa = __builtin_amdgcn_mfma_f32_32x32x16_bf16(Vf, Pf, Oa, 0, 0, 0);
                else         Ob = __builtin_amdgcn_mfma_f32_32x32x16_bf16(Vf, Pf, Ob, 0, 0, 0);
            }
        }
    }
    float s_tot = s + pair_other(s, lane);
    if (hi == 0) {
        size_t so = ((size_t)(b * Wn + w)) * Hn + q;
        sH[so] = s_tot;
    }
    unsigned short* ob = ohp + (((size_t)(b * Wn + w) * Hn + q) * Cn);
    #pragma unroll
    for (int ct = 0; ct < 2; ++ct) {
        #pragma unroll
        for (int rq = 0; rq < 4; ++rq) {
            int c0 = ct * 32 + rq * 8 + 4 * hi;
            const f32x16& O = ct ? Ob : Oa;
            u32x2 wv2;
            wv2[0] = cvtpk(O[rq * 4 + 0], O[rq * 4 + 1]);
            wv2[1] = cvtpk(O[rq * 4 + 2], O[rq * 4 + 3]);
            *(u32x2*)(ob + c0) = wv2;
        }
    }
}

// ---------------- K3: W-direction attention + joint combine ----------------
__global__ __launch_bounds__(512, 6) void k_attnW(
    const unsigned short* __restrict__ qbr, const unsigned short* __restrict__ kbr,
    const unsigned short* __restrict__ v_row,
    const unsigned short* __restrict__ ohp,
    const float* __restrict__ sH,
    const float* __restrict__ x, const float* __restrict__ gamma,
    float* __restrict__ out)
{
    __shared__ __align__(16) unsigned short Vl[16384];
    __shared__ __align__(16) unsigned short Kl[2048];
    int t = threadIdx.x, lane = t & 63, wv = t >> 6;
    int l31 = lane & 31, hi = lane >> 5;
    int bid = blockIdx.x;
    int b = bid >> 8, h = bid & 255;

    #pragma unroll
    for (int p = 0; p < 4; ++p) {
        int lin = p * 8192 + t * 16;
        int c = lin >> 9, off = lin & 511;
        const char* src = (const char*)(v_row + ((size_t)(b * Cn + c)) * HWn + (size_t)h * Wn) + off;
        f32x4 d = *(const f32x4*)src;
        unsigned dst = (unsigned)lin ^ ((unsigned)(c & 7) << 4);
        *(f32x4*)((char*)Vl + dst) = d;
    }
    const unsigned short* qb = qbr + ((size_t)(b * Hn + h)) * Wn * 8;
    const unsigned short* kb = kbr + ((size_t)(b * Hn + h)) * Wn * 8;
    if (t < 256) {
        *(bf16x8*)(Kl + t * 8) = *(const bf16x8*)(kb + (size_t)t * 8);
    }

    bf16x8 zer = {};
    int q = wv * 32 + l31;
    bf16x8 Qf;
    {
        bf16x8 v = *(const bf16x8*)(qb + (size_t)q * 8);
        Qf = (hi == 0) ? v : zer;
    }
    float g = gamma[0];
    __syncthreads();

    f32x16 Oa = {}, Ob = {};
    float s = 0.f;
    #pragma unroll
    for (int jt = 0; jt < 8; ++jt) {
        bf16x8 Kfc = *(const bf16x8*)(Kl + (jt * 32 + l31) * 8);
        if (hi) Kfc = zer;
        f32x16 zc = {};
        f32x16 e = __builtin_amdgcn_mfma_f32_32x32x16_bf16(Kfc, Qf, zc, 0, 0, 0);
        bf16x8 P0 = expPack(e, 0, s);
        bf16x8 P1 = expPack(e, 8, s);
        #pragma unroll
        for (int k2 = 0; k2 < 2; ++k2) {
            int ktA = jt * 2 + k2;
            bf16x8 Pf = k2 ? P1 : P0;
            #pragma unroll
            for (int ct = 0; ct < 2; ++ct) {
                int c = ct * 32 + l31;
                unsigned ad = ((unsigned)(c * 512 + ktA * 32 + hi * 16))
                            ^ ((unsigned)(c & 7) << 4);
                bf16x8 Vf = *(const bf16x8*)((const char*)Vl + ad);
                if (ct == 0) Oa = __builtin_amdgcn_mfma_f32_32x32x16_bf16(Vf, Pf, Oa, 0, 0, 0);
                else         Ob = __builtin_amdgcn_mfma_f32_32x32x16_bf16(Vf, Pf, Ob, 0, 0, 0);
            }
        }
    }
    float s_tot = s + pair_other(s, lane);
    size_t so = ((size_t)(b * Wn + q)) * Hn + h;
    float sh = sH[so];
    float gi = g / (s_tot + sh);
    const unsigned short* op = ohp + (((size_t)(b * Wn + q) * Hn + h) * Cn);
    #pragma unroll
    for (int ct = 0; ct < 2; ++ct) {
        #pragma unroll
        for (int rq = 0; rq < 4; ++rq) {
            int c0 = ct * 32 + rq * 8 + 4 * hi;
            u32x2 wv2 = *(const u32x2*)(op + c0);
            const f32x16& O = ct ? Ob : Oa;
            #pragma unroll
            for (int j = 0; j < 4; ++j) {
                int c = c0 + j;
                size_t idx = ((size_t)(b * Cn + c) * Hn + h) * Wn + q;
                unsigned short oh16 = (unsigned short)((wv2[j >> 1] >> ((j & 1) * 16)) & 0xffff);
                out[idx] = gi * (O[rq * 4 + j] + b2f(oh16)) + x[idx];
            }
        }
    }
}

extern "C" void kernel_launch(void* const* d_in, const int* in_sizes, int n_in,
                              void* d_out, int out_size, void* d_ws, size_t ws_size,
                              hipStream_t stream) {
    const float* x  = (const float*)d_in[0];
    const float* Wq = (const float*)d_in[1];
    const float* bq = (const float*)d_in[2];
    const float* Wk = (const float*)d_in[3];
    const float* bk = (const float*)d_in[4];
    const float* Wv = (const float*)d_in[5];
    const float* bv = (const float*)d_in[6];
    const float* gm = (const float*)d_in[7];
    float* out = (float*)d_out;
    char* ws = (char*)d_ws;

    const size_t BHW = (size_t)Bn * Hn * Wn; // 262144
    unsigned short* qbr = (unsigned short*)ws;
    unsigned short* kbr = qbr + 8 * BHW;
    unsigned short* v_row = kbr + 8 * BHW;
    unsigned short* vT    = v_row + 64 * BHW;
    unsigned short* ohp   = vT + 64 * BHW;
    float* sHb = (float*)(ohp + 64 * BHW);

    k_proj<<<512, 256, 0, stream>>>(x, Wq, bq, Wk, bk, Wv, bv,
                                    qbr, kbr, v_row);
    k_tr_bf16<<<Bn * (16384 / 64) * (256 / 64), 256, 0, stream>>>(v_row, vT, 16384, 256);
    k_attnH<<<Bn * Wn, 512, 0, stream>>>(qbr, kbr, vT, ohp, sHb);
    k_attnW<<<Bn * Hn, 512, 0, stream>>>(qbr, kbr, v_row, ohp, sHb, x, gm, out);
}

// Round 17
// 111.967 us; speedup vs baseline: 2.5787x; 2.5787x over previous
//
#include <hip/hip_runtime.h>

#define Bn 4
#define Cn 64
#define Hn 256
#define Wn 256
#define HWn 65536

typedef unsigned int u32;
typedef __attribute__((ext_vector_type(2))) unsigned int u32x2;
typedef __attribute__((ext_vector_type(8))) short bf16x8;
typedef __attribute__((ext_vector_type(4))) float f32x4;
typedef __attribute__((ext_vector_type(16))) float f32x16;

__device__ __forceinline__ unsigned short f2b(float f) {
    union { float f; unsigned u; } v; v.f = f;
    return (unsigned short)(v.u >> 16);
}
__device__ __forceinline__ float b2f(unsigned short s) {
    union { float f; unsigned u; } v; v.u = ((unsigned)s) << 16;
    return v.f;
}
__device__ __forceinline__ u32 cvtpk(float lo, float hi) {
    u32 r;
    asm("v_cvt_pk_bf16_f32 %0, %1, %2" : "=v"(r) : "v"(lo), "v"(hi));
    return r;
}
__device__ __forceinline__ void vswap(u32& a, u32& b) {
    asm volatile("v_permlane32_swap_b32 %0, %1" : "+v"(a), "+v"(b));
}
__device__ __forceinline__ float pair_other(float v, int lane) {
    union { float f; u32 u; } A; A.f = v;
    u32 a = A.u, b = A.u;
    vswap(a, b);
    union { u32 u; float f; } R; R.u = (lane < 32) ? b : a;
    return R.f;
}
__device__ __forceinline__ bf16x8 expPack(const f32x16& e, int base, float& ss) {
    float p0 = __expf(e[base + 0]), p1 = __expf(e[base + 1]);
    u32 A = cvtpk(p0, p1); ss += p0 + p1;
    float p4 = __expf(e[base + 4]), p5 = __expf(e[base + 5]);
    u32 B = cvtpk(p4, p5); ss += p4 + p5;
    vswap(A, B);
    float p2 = __expf(e[base + 2]), p3 = __expf(e[base + 3]);
    u32 C = cvtpk(p2, p3); ss += p2 + p3;
    float p6 = __expf(e[base + 6]), p7 = __expf(e[base + 7]);
    u32 D = cvtpk(p6, p7); ss += p6 + p7;
    vswap(C, D);
    union { u32 w[4]; bf16x8 v; } u;
    u.w[0] = A; u.w[1] = C; u.w[2] = B; u.w[3] = D;
    return u.v;
}

// ---------------- K1: persistent pipelined 1x1 conv projections ----------------
__global__ __launch_bounds__(256) void k_proj(
    const float* __restrict__ x,
    const float* __restrict__ Wq, const float* __restrict__ bq,
    const float* __restrict__ Wk, const float* __restrict__ bk,
    const float* __restrict__ Wv, const float* __restrict__ bv,
    unsigned short* __restrict__ qbr, unsigned short* __restrict__ kbr,
    unsigned short* __restrict__ v_row)
{
    __shared__ __align__(16) char Xl[2][16384];
    int t = threadIdx.x, lane = t & 63, wv = t >> 6;
    int row16 = lane & 15, g = lane >> 4;
    int u0 = blockIdx.x * 4;

    bf16x8 Af[5][2];
    #pragma unroll
    for (int m = 0; m < 5; ++m) {
        const float* wrow;
        if (m == 0) wrow = (row16 < 8) ? (Wq + row16 * 64) : (Wk + (row16 - 8) * 64);
        else        wrow = Wv + (size_t)((m - 1) * 16 + row16) * 64;
        #pragma unroll
        for (int ks = 0; ks < 2; ++ks) {
            int c0 = ks * 32 + g * 8;
            f32x4 w0 = *(const f32x4*)(wrow + c0);
            f32x4 w1 = *(const f32x4*)(wrow + c0 + 4);
            bf16x8 a;
            a[0] = (short)f2b(w0[0]); a[1] = (short)f2b(w0[1]);
            a[2] = (short)f2b(w0[2]); a[3] = (short)f2b(w0[3]);
            a[4] = (short)f2b(w1[0]); a[5] = (short)f2b(w1[1]);
            a[6] = (short)f2b(w1[2]); a[7] = (short)f2b(w1[3]);
            Af[m][ks] = a;
        }
    }

    int px4 = (t & 31) * 4;
    int cbase = (t >> 5) << 2;

    f32x4 st[2][8];
    {
        int u = u0;
        int b = u >> 9, rest = u & 511, h = rest >> 1, half = rest & 1;
        const float* xb2 = x + (size_t)b * Cn * HWn + (size_t)h * Wn + half * 128;
        #pragma unroll
        for (int pass = 0; pass < 2; ++pass) {
            int c0s = cbase + pass * 32;
            #pragma unroll
            for (int j = 0; j < 4; ++j)
                st[0][pass * 4 + j] = *(const f32x4*)(xb2 + (size_t)(c0s + j) * HWn + px4);
        }
    }

    #pragma unroll
    for (int ui = 0; ui < 4; ++ui) {
        int u = u0 + ui;
        int b = u >> 9, rest = u & 511, h = rest >> 1, half = rest & 1;
        int cur = ui & 1;

        #pragma unroll
        for (int pass = 0; pass < 2; ++pass) {
            int c0s = cbase + pass * 32;
            #pragma unroll
            for (int i = 0; i < 4; ++i) {
                int px = px4 + i;
                u32x2 w;
                w[0] = (u32)f2b(st[cur][pass * 4 + 0][i]) | ((u32)f2b(st[cur][pass * 4 + 1][i]) << 16);
                w[1] = (u32)f2b(st[cur][pass * 4 + 2][i]) | ((u32)f2b(st[cur][pass * 4 + 3][i]) << 16);
                unsigned addr = (unsigned)(px * 128)
                              + (((unsigned)(c0s * 2)) ^ ((((unsigned)px >> 3) & 7) << 4));
                *(u32x2*)(Xl[cur] + addr) = w;
            }
        }
        __syncthreads();

        if (ui < 3) {
            int un = u + 1;
            int bn = un >> 9, restn = un & 511, hn = restn >> 1, halfn = restn & 1;
            const float* xb2 = x + (size_t)bn * Cn * HWn + (size_t)hn * Wn + halfn * 128;
            #pragma unroll
            for (int pass = 0; pass < 2; ++pass) {
                int c0s = cbase + pass * 32;
                #pragma unroll
                for (int j = 0; j < 4; ++j)
                    st[cur ^ 1][pass * 4 + j] = *(const f32x4*)(xb2 + (size_t)(c0s + j) * HWn + px4);
            }
        }

        f32x4 acc[5][2];
        #pragma unroll
        for (int m = 0; m < 5; ++m)
            #pragma unroll
            for (int nt = 0; nt < 2; ++nt)
                acc[m][nt] = (f32x4){0.f, 0.f, 0.f, 0.f};

        #pragma unroll
        for (int nt = 0; nt < 2; ++nt) {
            int px = wv * 32 + nt * 16 + row16;
            #pragma unroll
            for (int ks = 0; ks < 2; ++ks) {
                int c0 = ks * 32 + g * 8;
                unsigned addr = (unsigned)(px * 128)
                              + (((unsigned)(c0 * 2)) ^ ((((unsigned)px >> 3) & 7) << 4));
                bf16x8 bf = *(const bf16x8*)(Xl[cur] + addr);
                #pragma unroll
                for (int m = 0; m < 5; ++m)
                    acc[m][nt] = __builtin_amdgcn_mfma_f32_16x16x32_bf16(Af[m][ks], bf, acc[m][nt], 0, 0, 0);
            }
        }

        f32x4 bQK = (g < 2) ? *(const f32x4*)(bq + g * 4)
                            : *(const f32x4*)(bk + (g - 2) * 4);
        #pragma unroll
        for (int nt = 0; nt < 2; ++nt) {
            int p = half * 128 + wv * 32 + nt * 16 + row16;
            f32x4 d = acc[0][nt];
            d[0] += bQK[0]; d[1] += bQK[1]; d[2] += bQK[2]; d[3] += bQK[3];
            u32 w0 = (u32)f2b(d[0]) | ((u32)f2b(d[1]) << 16);
            u32 w1 = (u32)f2b(d[2]) | ((u32)f2b(d[3]) << 16);
            size_t roff = ((size_t)(b * Hn + h) * Wn + p) * 8 + (size_t)((g & 1) * 4);
            if (g < 2) {
                *(u32*)(qbr + roff) = w0; *(u32*)(qbr + roff + 2) = w1;
            } else {
                *(u32*)(kbr + roff) = w0; *(u32*)(kbr + roff + 2) = w1;
            }
            #pragma unroll
            for (int m = 1; m < 5; ++m) {
                f32x4 bV = *(const f32x4*)(bv + (m - 1) * 16 + g * 4);
                unsigned short* vp = v_row + (size_t)b * Cn * HWn
                                   + (size_t)((m - 1) * 16 + g * 4) * HWn
                                   + (size_t)h * Wn + p;
                #pragma unroll
                for (int r = 0; r < 4; ++r)
                    vp[(size_t)r * HWn] = f2b(acc[m][nt][r] + bV[r]);
            }
        }
    }
}

// ---------------- bf16 tiled transpose (v_row -> vT only) ----------------
__global__ __launch_bounds__(256) void k_tr_bf16(
    const unsigned short* __restrict__ in, unsigned short* __restrict__ out,
    int R, int Ccols)
{
    __shared__ unsigned short tile[64][66];
    int t = threadIdx.x;
    int lr = t >> 6, lc = t & 63;
    int tilesC = Ccols >> 6;
    int per_b = (R >> 6) * tilesC;
    int bid = blockIdx.x;
    int b = bid / per_b;
    int rem = bid - b * per_b;
    int r0 = (rem / tilesC) << 6;
    int c0 = (rem - (rem / tilesC) * tilesC) << 6;
    const unsigned short* ip = in + (size_t)b * R * Ccols;
    unsigned short* op = out + (size_t)b * R * Ccols;
    #pragma unroll
    for (int i = 0; i < 16; ++i) {
        int r = lr * 16 + i;
        tile[r][lc] = ip[(size_t)(r0 + r) * Ccols + c0 + lc];
    }
    __syncthreads();
    #pragma unroll
    for (int i = 0; i < 16; ++i) {
        int c = lr * 16 + i;
        op[(size_t)(c0 + c) * R + r0 + lc] = tile[lc][c];
    }
}

// ---------------- K2: H-direction attention ----------------
// R17: 512-thread retry with launch_bounds(512,2) — R16's (512,6) capped
// VGPR at 85 < the kernel's ~92 live set -> forced spill (WRITE 65->299MB).
// Rule: never bound below known live VGPR. LDS 36.9KB shared by 8 waves.
__global__ __launch_bounds__(512, 2) void k_attnH(
    const unsigned short* __restrict__ qbr, const unsigned short* __restrict__ kbr,
    const unsigned short* __restrict__ vT,
    unsigned short* __restrict__ ohp,
    float* __restrict__ sH)
{
    __shared__ __align__(16) unsigned short Vl[16384];
    __shared__ __align__(16) unsigned short Kl[2048];
    int t = threadIdx.x, lane = t & 63, wv = t >> 6;
    int l31 = lane & 31, hi = lane >> 5;
    int bid = blockIdx.x;
    int b = bid >> 8, w = bid & 255;

    const char* vsrc = (const char*)(vT + ((size_t)(b * Wn + w)) * Cn * Hn);
    #pragma unroll
    for (int p = 0; p < 4; ++p) {
        int lin = p * 8192 + t * 16;
        int c = lin >> 9;
        f32x4 d = *(const f32x4*)(vsrc + lin);
        unsigned dst = (unsigned)lin ^ ((unsigned)(c & 7) << 4);
        *(f32x4*)((char*)Vl + dst) = d;
    }
    if (t < 256) {
        *(bf16x8*)(Kl + t * 8) = *(const bf16x8*)(kbr + ((size_t)(b * Hn + t) * Wn + w) * 8);
    }

    bf16x8 zer = {};
    int qtA = wv;
    int q = qtA * 32 + l31;
    bf16x8 Qf;
    {
        bf16x8 v = *(const bf16x8*)(qbr + ((size_t)(b * Hn + q) * Wn + w) * 8);
        Qf = (hi == 0) ? v : zer;
    }
    __syncthreads();

    f32x16 Oa = {}, Ob = {};
    float s = 0.f;
    #pragma unroll
    for (int jt = 0; jt < 8; ++jt) {
        bf16x8 Kfc = *(const bf16x8*)(Kl + (jt * 32 + l31) * 8);
        if (hi) Kfc = zer;
        f32x16 zc = {};
        f32x16 e = __builtin_amdgcn_mfma_f32_32x32x16_bf16(Kfc, Qf, zc, 0, 0, 0);
        if (jt == qtA) {
            #pragma unroll
            for (int r = 0; r < 16; ++r) {
                int rl = (r & 3) + 8 * (r >> 2) + 4 * hi;
                e[r] = (rl == l31) ? -1e30f : e[r];
            }
        }
        bf16x8 P0 = expPack(e, 0, s);
        bf16x8 P1 = expPack(e, 8, s);
        #pragma unroll
        for (int k2 = 0; k2 < 2; ++k2) {
            int ktA = jt * 2 + k2;
            bf16x8 Pf = k2 ? P1 : P0;
            #pragma unroll
            for (int ct = 0; ct < 2; ++ct) {
                int c = ct * 32 + l31;
                unsigned ad = ((unsigned)(c * 512 + ktA * 32 + hi * 16))
                            ^ ((unsigned)(c & 7) << 4);
                bf16x8 Vf = *(const bf16x8*)((const char*)Vl + ad);
                if (ct == 0) Oa = __builtin_amdgcn_mfma_f32_32x32x16_bf16(Vf, Pf, Oa, 0, 0, 0);
                else         Ob = __builtin_amdgcn_mfma_f32_32x32x16_bf16(Vf, Pf, Ob, 0, 0, 0);
            }
        }
    }
    float s_tot = s + pair_other(s, lane);
    if (hi == 0) {
        size_t so = ((size_t)(b * Wn + w)) * Hn + q;
        sH[so] = s_tot;
    }
    unsigned short* ob = ohp + (((size_t)(b * Wn + w) * Hn + q) * Cn);
    #pragma unroll
    for (int ct = 0; ct < 2; ++ct) {
        #pragma unroll
        for (int rq = 0; rq < 4; ++rq) {
            int c0 = ct * 32 + rq * 8 + 4 * hi;
            const f32x16& O = ct ? Ob : Oa;
            u32x2 wv2;
            wv2[0] = cvtpk(O[rq * 4 + 0], O[rq * 4 + 1]);
            wv2[1] = cvtpk(O[rq * 4 + 2], O[rq * 4 + 3]);
            *(u32x2*)(ob + c0) = wv2;
        }
    }
}

// ---------------- K3: W-direction attention + joint combine ----------------
__global__ __launch_bounds__(512, 2) void k_attnW(
    const unsigned short* __restrict__ qbr, const unsigned short* __restrict__ kbr,
    const unsigned short* __restrict__ v_row,
    const unsigned short* __restrict__ ohp,
    const float* __restrict__ sH,
    const float* __restrict__ x, const float* __restrict__ gamma,
    float* __restrict__ out)
{
    __shared__ __align__(16) unsigned short Vl[16384];
    __shared__ __align__(16) unsigned short Kl[2048];
    int t = threadIdx.x, lane = t & 63, wv = t >> 6;
    int l31 = lane & 31, hi = lane >> 5;
    int bid = blockIdx.x;
    int b = bid >> 8, h = bid & 255;

    #pragma unroll
    for (int p = 0; p < 4; ++p) {
        int lin = p * 8192 + t * 16;
        int c = lin >> 9, off = lin & 511;
        const char* src = (const char*)(v_row + ((size_t)(b * Cn + c)) * HWn + (size_t)h * Wn) + off;
        f32x4 d = *(const f32x4*)src;
        unsigned dst = (unsigned)lin ^ ((unsigned)(c & 7) << 4);
        *(f32x4*)((char*)Vl + dst) = d;
    }
    const unsigned short* qb = qbr + ((size_t)(b * Hn + h)) * Wn * 8;
    const unsigned short* kb = kbr + ((size_t)(b * Hn + h)) * Wn * 8;
    if (t < 256) {
        *(bf16x8*)(Kl + t * 8) = *(const bf16x8*)(kb + (size_t)t * 8);
    }

    bf16x8 zer = {};
    int q = wv * 32 + l31;
    bf16x8 Qf;
    {
        bf16x8 v = *(const bf16x8*)(qb + (size_t)q * 8);
        Qf = (hi == 0) ? v : zer;
    }
    float g = gamma[0];
    __syncthreads();

    f32x16 Oa = {}, Ob = {};
    float s = 0.f;
    #pragma unroll
    for (int jt = 0; jt < 8; ++jt) {
        bf16x8 Kfc = *(const bf16x8*)(Kl + (jt * 32 + l31) * 8);
        if (hi) Kfc = zer;
        f32x16 zc = {};
        f32x16 e = __builtin_amdgcn_mfma_f32_32x32x16_bf16(Kfc, Qf, zc, 0, 0, 0);
        bf16x8 P0 = expPack(e, 0, s);
        bf16x8 P1 = expPack(e, 8, s);
        #pragma unroll
        for (int k2 = 0; k2 < 2; ++k2) {
            int ktA = jt * 2 + k2;
            bf16x8 Pf = k2 ? P1 : P0;
            #pragma unroll
            for (int ct = 0; ct < 2; ++ct) {
                int c = ct * 32 + l31;
                unsigned ad = ((unsigned)(c * 512 + ktA * 32 + hi * 16))
                            ^ ((unsigned)(c & 7) << 4);
                bf16x8 Vf = *(const bf16x8*)((const char*)Vl + ad);
                if (ct == 0) Oa = __builtin_amdgcn_mfma_f32_32x32x16_bf16(Vf, Pf, Oa, 0, 0, 0);
                else         Ob = __builtin_amdgcn_mfma_f32_32x32x16_bf16(Vf, Pf, Ob, 0, 0, 0);
            }
        }
    }
    float s_tot = s + pair_other(s, lane);
    size_t so = ((size_t)(b * Wn + q)) * Hn + h;
    float sh = sH[so];
    float gi = g / (s_tot + sh);
    const unsigned short* op = ohp + (((size_t)(b * Wn + q) * Hn + h) * Cn);
    #pragma unroll
    for (int ct = 0; ct < 2; ++ct) {
        #pragma unroll
        for (int rq = 0; rq < 4; ++rq) {
            int c0 = ct * 32 + rq * 8 + 4 * hi;
            u32x2 wv2 = *(const u32x2*)(op + c0);
            const f32x16& O = ct ? Ob : Oa;
            #pragma unroll
            for (int j = 0; j < 4; ++j) {
                int c = c0 + j;
                size_t idx = ((size_t)(b * Cn + c) * Hn + h) * Wn + q;
                unsigned short oh16 = (unsigned short)((wv2[j >> 1] >> ((j & 1) * 16)) & 0xffff);
                out[idx] = gi * (O[rq * 4 + j] + b2f(oh16)) + x[idx];
            }
        }
    }
}

extern "C" void kernel_launch(void* const* d_in, const int* in_sizes, int n_in,
                              void* d_out, int out_size, void* d_ws, size_t ws_size,
                              hipStream_t stream) {
    const float* x  = (const float*)d_in[0];
    const float* Wq = (const float*)d_in[1];
    const float* bq = (const float*)d_in[2];
    const float* Wk = (const float*)d_in[3];
    const float* bk = (const float*)d_in[4];
    const float* Wv = (const float*)d_in[5];
    const float* bv = (const float*)d_in[6];
    const float* gm = (const float*)d_in[7];
    float* out = (float*)d_out;
    char* ws = (char*)d_ws;

    const size_t BHW = (size_t)Bn * Hn * Wn; // 262144
    unsigned short* qbr = (unsigned short*)ws;
    unsigned short* kbr = qbr + 8 * BHW;
    unsigned short* v_row = kbr + 8 * BHW;
    unsigned short* vT    = v_row + 64 * BHW;
    unsigned short* ohp   = vT + 64 * BHW;
    float* sHb = (float*)(ohp + 64 * BHW);

    k_proj<<<512, 256, 0, stream>>>(x, Wq, bq, Wk, bk, Wv, bv,
                                    qbr, kbr, v_row);
    k_tr_bf16<<<Bn * (16384 / 64) * (256 / 64), 256, 0, stream>>>(v_row, vT, 16384, 256);
    k_attnH<<<Bn * Wn, 512, 0, stream>>>(qbr, kbr, vT, ohp, sHb);
    k_attnW<<<Bn * Hn, 512, 0, stream>>>(qbr, kbr, v_row, ohp, sHb, x, gm, out);
}

// Round 18
// 107.735 us; speedup vs baseline: 2.6800x; 1.0393x over previous
//
#include <hip/hip_runtime.h>

#define Bn 4
#define Cn 64
#define Hn 256
#define Wn 256
#define HWn 65536

typedef unsigned int u32;
typedef __attribute__((ext_vector_type(2))) unsigned int u32x2;
typedef __attribute__((ext_vector_type(8))) short bf16x8;
typedef __attribute__((ext_vector_type(4))) float f32x4;
typedef __attribute__((ext_vector_type(16))) float f32x16;

__device__ __forceinline__ unsigned short f2b(float f) {
    union { float f; unsigned u; } v; v.f = f;
    return (unsigned short)(v.u >> 16);
}
__device__ __forceinline__ float b2f(unsigned short s) {
    union { float f; unsigned u; } v; v.u = ((unsigned)s) << 16;
    return v.f;
}
__device__ __forceinline__ u32 cvtpk(float lo, float hi) {
    u32 r;
    asm("v_cvt_pk_bf16_f32 %0, %1, %2" : "=v"(r) : "v"(lo), "v"(hi));
    return r;
}
__device__ __forceinline__ void vswap(u32& a, u32& b) {
    asm volatile("v_permlane32_swap_b32 %0, %1" : "+v"(a), "+v"(b));
}
__device__ __forceinline__ float pair_other(float v, int lane) {
    union { float f; u32 u; } A; A.f = v;
    u32 a = A.u, b = A.u;
    vswap(a, b);
    union { u32 u; float f; } R; R.u = (lane < 32) ? b : a;
    return R.f;
}
__device__ __forceinline__ bf16x8 expPack(const f32x16& e, int base, float& ss) {
    float p0 = __expf(e[base + 0]), p1 = __expf(e[base + 1]);
    u32 A = cvtpk(p0, p1); ss += p0 + p1;
    float p4 = __expf(e[base + 4]), p5 = __expf(e[base + 5]);
    u32 B = cvtpk(p4, p5); ss += p4 + p5;
    vswap(A, B);
    float p2 = __expf(e[base + 2]), p3 = __expf(e[base + 3]);
    u32 C = cvtpk(p2, p3); ss += p2 + p3;
    float p6 = __expf(e[base + 6]), p7 = __expf(e[base + 7]);
    u32 D = cvtpk(p6, p7); ss += p6 + p7;
    vswap(C, D);
    union { u32 w[4]; bf16x8 v; } u;
    u.w[0] = A; u.w[1] = C; u.w[2] = B; u.w[3] = D;
    return u.v;
}

// ---------------- K1: persistent pipelined 1x1 conv projections ----------------
__global__ __launch_bounds__(256) void k_proj(
    const float* __restrict__ x,
    const float* __restrict__ Wq, const float* __restrict__ bq,
    const float* __restrict__ Wk, const float* __restrict__ bk,
    const float* __restrict__ Wv, const float* __restrict__ bv,
    unsigned short* __restrict__ qbr, unsigned short* __restrict__ kbr,
    unsigned short* __restrict__ v_row)
{
    __shared__ __align__(16) char Xl[2][16384];
    int t = threadIdx.x, lane = t & 63, wv = t >> 6;
    int row16 = lane & 15, g = lane >> 4;
    int u0 = blockIdx.x * 4;

    bf16x8 Af[5][2];
    #pragma unroll
    for (int m = 0; m < 5; ++m) {
        const float* wrow;
        if (m == 0) wrow = (row16 < 8) ? (Wq + row16 * 64) : (Wk + (row16 - 8) * 64);
        else        wrow = Wv + (size_t)((m - 1) * 16 + row16) * 64;
        #pragma unroll
        for (int ks = 0; ks < 2; ++ks) {
            int c0 = ks * 32 + g * 8;
            f32x4 w0 = *(const f32x4*)(wrow + c0);
            f32x4 w1 = *(const f32x4*)(wrow + c0 + 4);
            bf16x8 a;
            a[0] = (short)f2b(w0[0]); a[1] = (short)f2b(w0[1]);
            a[2] = (short)f2b(w0[2]); a[3] = (short)f2b(w0[3]);
            a[4] = (short)f2b(w1[0]); a[5] = (short)f2b(w1[1]);
            a[6] = (short)f2b(w1[2]); a[7] = (short)f2b(w1[3]);
            Af[m][ks] = a;
        }
    }

    int px4 = (t & 31) * 4;
    int cbase = (t >> 5) << 2;

    f32x4 st[2][8];
    {
        int u = u0;
        int b = u >> 9, rest = u & 511, h = rest >> 1, half = rest & 1;
        const float* xb2 = x + (size_t)b * Cn * HWn + (size_t)h * Wn + half * 128;
        #pragma unroll
        for (int pass = 0; pass < 2; ++pass) {
            int c0s = cbase + pass * 32;
            #pragma unroll
            for (int j = 0; j < 4; ++j)
                st[0][pass * 4 + j] = *(const f32x4*)(xb2 + (size_t)(c0s + j) * HWn + px4);
        }
    }

    #pragma unroll
    for (int ui = 0; ui < 4; ++ui) {
        int u = u0 + ui;
        int b = u >> 9, rest = u & 511, h = rest >> 1, half = rest & 1;
        int cur = ui & 1;

        #pragma unroll
        for (int pass = 0; pass < 2; ++pass) {
            int c0s = cbase + pass * 32;
            #pragma unroll
            for (int i = 0; i < 4; ++i) {
                int px = px4 + i;
                u32x2 w;
                w[0] = (u32)f2b(st[cur][pass * 4 + 0][i]) | ((u32)f2b(st[cur][pass * 4 + 1][i]) << 16);
                w[1] = (u32)f2b(st[cur][pass * 4 + 2][i]) | ((u32)f2b(st[cur][pass * 4 + 3][i]) << 16);
                unsigned addr = (unsigned)(px * 128)
                              + (((unsigned)(c0s * 2)) ^ ((((unsigned)px >> 3) & 7) << 4));
                *(u32x2*)(Xl[cur] + addr) = w;
            }
        }
        __syncthreads();

        if (ui < 3) {
            int un = u + 1;
            int bn = un >> 9, restn = un & 511, hn = restn >> 1, halfn = restn & 1;
            const float* xb2 = x + (size_t)bn * Cn * HWn + (size_t)hn * Wn + halfn * 128;
            #pragma unroll
            for (int pass = 0; pass < 2; ++pass) {
                int c0s = cbase + pass * 32;
                #pragma unroll
                for (int j = 0; j < 4; ++j)
                    st[cur ^ 1][pass * 4 + j] = *(const f32x4*)(xb2 + (size_t)(c0s + j) * HWn + px4);
            }
        }

        f32x4 acc[5][2];
        #pragma unroll
        for (int m = 0; m < 5; ++m)
            #pragma unroll
            for (int nt = 0; nt < 2; ++nt)
                acc[m][nt] = (f32x4){0.f, 0.f, 0.f, 0.f};

        #pragma unroll
        for (int nt = 0; nt < 2; ++nt) {
            int px = wv * 32 + nt * 16 + row16;
            #pragma unroll
            for (int ks = 0; ks < 2; ++ks) {
                int c0 = ks * 32 + g * 8;
                unsigned addr = (unsigned)(px * 128)
                              + (((unsigned)(c0 * 2)) ^ ((((unsigned)px >> 3) & 7) << 4));
                bf16x8 bf = *(const bf16x8*)(Xl[cur] + addr);
                #pragma unroll
                for (int m = 0; m < 5; ++m)
                    acc[m][nt] = __builtin_amdgcn_mfma_f32_16x16x32_bf16(Af[m][ks], bf, acc[m][nt], 0, 0, 0);
            }
        }

        f32x4 bQK = (g < 2) ? *(const f32x4*)(bq + g * 4)
                            : *(const f32x4*)(bk + (g - 2) * 4);
        #pragma unroll
        for (int nt = 0; nt < 2; ++nt) {
            int p = half * 128 + wv * 32 + nt * 16 + row16;
            f32x4 d = acc[0][nt];
            d[0] += bQK[0]; d[1] += bQK[1]; d[2] += bQK[2]; d[3] += bQK[3];
            u32 w0 = (u32)f2b(d[0]) | ((u32)f2b(d[1]) << 16);
            u32 w1 = (u32)f2b(d[2]) | ((u32)f2b(d[3]) << 16);
            size_t roff = ((size_t)(b * Hn + h) * Wn + p) * 8 + (size_t)((g & 1) * 4);
            if (g < 2) {
                *(u32*)(qbr + roff) = w0; *(u32*)(qbr + roff + 2) = w1;
            } else {
                *(u32*)(kbr + roff) = w0; *(u32*)(kbr + roff + 2) = w1;
            }
            #pragma unroll
            for (int m = 1; m < 5; ++m) {
                f32x4 bV = *(const f32x4*)(bv + (m - 1) * 16 + g * 4);
                unsigned short* vp = v_row + (size_t)b * Cn * HWn
                                   + (size_t)((m - 1) * 16 + g * 4) * HWn
                                   + (size_t)h * Wn + p;
                #pragma unroll
                for (int r = 0; r < 4; ++r)
                    vp[(size_t)r * HWn] = f2b(acc[m][nt][r] + bV[r]);
            }
        }
    }
}

// ---------------- bf16 tiled transpose (v_row -> vT only) ----------------
__global__ __launch_bounds__(256) void k_tr_bf16(
    const unsigned short* __restrict__ in, unsigned short* __restrict__ out,
    int R, int Ccols)
{
    __shared__ unsigned short tile[64][66];
    int t = threadIdx.x;
    int lr = t >> 6, lc = t & 63;
    int tilesC = Ccols >> 6;
    int per_b = (R >> 6) * tilesC;
    int bid = blockIdx.x;
    int b = bid / per_b;
    int rem = bid - b * per_b;
    int r0 = (rem / tilesC) << 6;
    int c0 = (rem - (rem / tilesC) * tilesC) << 6;
    const unsigned short* ip = in + (size_t)b * R * Ccols;
    unsigned short* op = out + (size_t)b * R * Ccols;
    #pragma unroll
    for (int i = 0; i < 16; ++i) {
        int r = lr * 16 + i;
        tile[r][lc] = ip[(size_t)(r0 + r) * Ccols + c0 + lc];
    }
    __syncthreads();
    #pragma unroll
    for (int i = 0; i < 16; ++i) {
        int c = lr * 16 + i;
        op[(size_t)(c0 + c) * R + r0 + lc] = tile[lc][c];
    }
}

// ---------------- K2: H-direction attention (R15 best config) ----------------
// R17 post-mortem: 512-thread variant regressed (43.6 vs 43.8 but attnH
// worse); occupancy/VALU/fetch levers all null on attnW across R9/R13/R17
// A/B matrix -> latency-structure-bound. Reverted to R15 exactly.
__global__ __launch_bounds__(256, 2) void k_attnH(
    const unsigned short* __restrict__ qbr, const unsigned short* __restrict__ kbr,
    const unsigned short* __restrict__ vT,
    unsigned short* __restrict__ ohp,
    float* __restrict__ sH)
{
    __shared__ __align__(16) unsigned short Vl[16384];
    int t = threadIdx.x, lane = t & 63, wv = t >> 6;
    int l31 = lane & 31, hi = lane >> 5;
    int bid = blockIdx.x;
    int qh = bid & 1;
    int rest = bid >> 1, b = rest >> 8, w = rest & 255;

    const char* vsrc = (const char*)(vT + ((size_t)(b * Wn + w)) * Cn * Hn);
    #pragma unroll
    for (int p = 0; p < 8; ++p) {
        int lin = p * 4096 + t * 16;
        int c = lin >> 9;
        f32x4 d = *(const f32x4*)(vsrc + lin);
        unsigned dst = (unsigned)lin ^ ((unsigned)(c & 7) << 4);
        *(f32x4*)((char*)Vl + dst) = d;
    }

    bf16x8 zer = {};
    int qtA = qh * 4 + wv;
    int q = qtA * 32 + l31;
    bf16x8 Qf, Kf[8];
    {
        bf16x8 v = *(const bf16x8*)(qbr + ((size_t)(b * Hn + q) * Wn + w) * 8);
        Qf = (hi == 0) ? v : zer;
    }
    #pragma unroll
    for (int jt = 0; jt < 8; ++jt) {
        int j = jt * 32 + l31;
        bf16x8 v = *(const bf16x8*)(kbr + ((size_t)(b * Hn + j) * Wn + w) * 8);
        Kf[jt] = (hi == 0) ? v : zer;
    }
    __syncthreads();

    f32x16 Oa = {}, Ob = {};
    float s = 0.f;
    #pragma unroll
    for (int jt = 0; jt < 8; ++jt) {
        f32x16 zc = {};
        f32x16 e = __builtin_amdgcn_mfma_f32_32x32x16_bf16(Kf[jt], Qf, zc, 0, 0, 0);
        if (jt == qtA) {
            #pragma unroll
            for (int r = 0; r < 16; ++r) {
                int rl = (r & 3) + 8 * (r >> 2) + 4 * hi;
                e[r] = (rl == l31) ? -1e30f : e[r];
            }
        }
        bf16x8 P0 = expPack(e, 0, s);
        bf16x8 P1 = expPack(e, 8, s);
        #pragma unroll
        for (int k2 = 0; k2 < 2; ++k2) {
            int ktA = jt * 2 + k2;
            bf16x8 Pf = k2 ? P1 : P0;
            #pragma unroll
            for (int ct = 0; ct < 2; ++ct) {
                int c = ct * 32 + l31;
                unsigned ad = ((unsigned)(c * 512 + ktA * 32 + hi * 16))
                            ^ ((unsigned)(c & 7) << 4);
                bf16x8 Vf = *(const bf16x8*)((const char*)Vl + ad);
                if (ct == 0) Oa = __builtin_amdgcn_mfma_f32_32x32x16_bf16(Vf, Pf, Oa, 0, 0, 0);
                else         Ob = __builtin_amdgcn_mfma_f32_32x32x16_bf16(Vf, Pf, Ob, 0, 0, 0);
            }
        }
    }
    float s_tot = s + pair_other(s, lane);
    if (hi == 0) {
        size_t so = ((size_t)(b * Wn + w)) * Hn + q;
        sH[so] = s_tot;
    }
    unsigned short* ob = ohp + (((size_t)(b * Wn + w) * Hn + q) * Cn);
    #pragma unroll
    for (int ct = 0; ct < 2; ++ct) {
        #pragma unroll
        for (int rq = 0; rq < 4; ++rq) {
            int c0 = ct * 32 + rq * 8 + 4 * hi;
            const f32x16& O = ct ? Ob : Oa;
            u32x2 wv2;
            wv2[0] = cvtpk(O[rq * 4 + 0], O[rq * 4 + 1]);
            wv2[1] = cvtpk(O[rq * 4 + 2], O[rq * 4 + 3]);
            *(u32x2*)(ob + c0) = wv2;
        }
    }
}

// ---------------- K3: W-direction attention + joint combine (R15 best config) ----------------
__global__ __launch_bounds__(256, 2) void k_attnW(
    const unsigned short* __restrict__ qbr, const unsigned short* __restrict__ kbr,
    const unsigned short* __restrict__ v_row,
    const unsigned short* __restrict__ ohp,
    const float* __restrict__ sH,
    const float* __restrict__ x, const float* __restrict__ gamma,
    float* __restrict__ out)
{
    __shared__ __align__(16) unsigned short Vl[16384];
    int t = threadIdx.x, lane = t & 63, wv = t >> 6;
    int l31 = lane & 31, hi = lane >> 5;
    int bid = blockIdx.x;
    int qh = bid & 1;
    int rest = bid >> 1, b = rest >> 8, h = rest & 255;

    #pragma unroll
    for (int p = 0; p < 8; ++p) {
        int lin = p * 4096 + t * 16;
        int c = lin >> 9, off = lin & 511;
        const char* src = (const char*)(v_row + ((size_t)(b * Cn + c)) * HWn + (size_t)h * Wn) + off;
        f32x4 d = *(const f32x4*)src;
        unsigned dst = (unsigned)lin ^ ((unsigned)(c & 7) << 4);
        *(f32x4*)((char*)Vl + dst) = d;
    }

    const unsigned short* qb = qbr + ((size_t)(b * Hn + h)) * Wn * 8;
    const unsigned short* kb = kbr + ((size_t)(b * Hn + h)) * Wn * 8;
    bf16x8 zer = {};
    int q = qh * 128 + wv * 32 + l31;
    bf16x8 Qf, Kf[8];
    {
        bf16x8 v = *(const bf16x8*)(qb + (size_t)q * 8);
        Qf = (hi == 0) ? v : zer;
    }
    #pragma unroll
    for (int jt = 0; jt < 8; ++jt) {
        int j = jt * 32 + l31;
        bf16x8 v = *(const bf16x8*)(kb + (size_t)j * 8);
        Kf[jt] = (hi == 0) ? v : zer;
    }
    float g = gamma[0];
    __syncthreads();

    f32x16 Oa = {}, Ob = {};
    float s = 0.f;
    #pragma unroll
    for (int jt = 0; jt < 8; ++jt) {
        f32x16 zc = {};
        f32x16 e = __builtin_amdgcn_mfma_f32_32x32x16_bf16(Kf[jt], Qf, zc, 0, 0, 0);
        bf16x8 P0 = expPack(e, 0, s);
        bf16x8 P1 = expPack(e, 8, s);
        #pragma unroll
        for (int k2 = 0; k2 < 2; ++k2) {
            int ktA = jt * 2 + k2;
            bf16x8 Pf = k2 ? P1 : P0;
            #pragma unroll
            for (int ct = 0; ct < 2; ++ct) {
                int c = ct * 32 + l31;
                unsigned ad = ((unsigned)(c * 512 + ktA * 32 + hi * 16))
                            ^ ((unsigned)(c & 7) << 4);
                bf16x8 Vf = *(const bf16x8*)((const char*)Vl + ad);
                if (ct == 0) Oa = __builtin_amdgcn_mfma_f32_32x32x16_bf16(Vf, Pf, Oa, 0, 0, 0);
                else         Ob = __builtin_amdgcn_mfma_f32_32x32x16_bf16(Vf, Pf, Ob, 0, 0, 0);
            }
        }
    }
    float s_tot = s + pair_other(s, lane);
    size_t so = ((size_t)(b * Wn + q)) * Hn + h;
    float sh = sH[so];
    float gi = g / (s_tot + sh);
    const unsigned short* op = ohp + (((size_t)(b * Wn + q) * Hn + h) * Cn);
    #pragma unroll
    for (int ct = 0; ct < 2; ++ct) {
        #pragma unroll
        for (int rq = 0; rq < 4; ++rq) {
            int c0 = ct * 32 + rq * 8 + 4 * hi;
            u32x2 wv2 = *(const u32x2*)(op + c0);
            const f32x16& O = ct ? Ob : Oa;
            #pragma unroll
            for (int j = 0; j < 4; ++j) {
                int c = c0 + j;
                size_t idx = ((size_t)(b * Cn + c) * Hn + h) * Wn + q;
                unsigned short oh16 = (unsigned short)((wv2[j >> 1] >> ((j & 1) * 16)) & 0xffff);
                out[idx] = gi * (O[rq * 4 + j] + b2f(oh16)) + x[idx];
            }
        }
    }
}

extern "C" void kernel_launch(void* const* d_in, const int* in_sizes, int n_in,
                              void* d_out, int out_size, void* d_ws, size_t ws_size,
                              hipStream_t stream) {
    const float* x  = (const float*)d_in[0];
    const float* Wq = (const float*)d_in[1];
    const float* bq = (const float*)d_in[2];
    const float* Wk = (const float*)d_in[3];
    const float* bk = (const float*)d_in[4];
    const float* Wv = (const float*)d_in[5];
    const float* bv = (const float*)d_in[6];
    const float* gm = (const float*)d_in[7];
    float* out = (float*)d_out;
    char* ws = (char*)d_ws;

    const size_t BHW = (size_t)Bn * Hn * Wn; // 262144
    unsigned short* qbr = (unsigned short*)ws;
    unsigned short* kbr = qbr + 8 * BHW;
    unsigned short* v_row = kbr + 8 * BHW;
    unsigned short* vT    = v_row + 64 * BHW;
    unsigned short* ohp   = vT + 64 * BHW;
    float* sHb = (float*)(ohp + 64 * BHW);

    k_proj<<<512, 256, 0, stream>>>(x, Wq, bq, Wk, bk, Wv, bv,
                                    qbr, kbr, v_row);
    k_tr_bf16<<<Bn * (16384 / 64) * (256 / 64), 256, 0, stream>>>(v_row, vT, 16384, 256);
    k_attnH<<<Bn * Wn * 2, 256, 0, stream>>>(qbr, kbr, vT, ohp, sHb);
    k_attnW<<<Bn * Hn * 2, 256, 0, stream>>>(qbr, kbr, v_row, ohp, sHb, x, gm, out);
}